// Round 9
// baseline (119.330 us; speedup 1.0000x reference)
//
#include <hip/hip_runtime.h>
#include <hip/hip_bf16.h>

#define N 16384
#define NTL (N / 16)             // 1024 point-tiles per cloud
#define AQT 16                   // a-tiles per wave
#define WAVES 4                  // waves per block
#define ABLK (AQT * WAVES)       // 64 a-tiles per block
#define NAG (NTL / ABLK)         // 16 a-groups
#define JSPLIT 32                // j-chunks
#define JCH (NTL / JSPLIT)       // 32 j-tiles per chunk (512 cols)
#define GRID (NAG * JSPLIT)      // 512 blocks x 256 threads
#define INF_BITS 0x7F800000
#define ONE_BF 0x3F80u

typedef __bf16 bf16x8 __attribute__((ext_vector_type(8)));
typedef float f32x4 __attribute__((ext_vector_type(4)));

// ---- memory plan (total ws use = 640 KB, exactly the r1-r5 PROVEN level) ----
// ws:      [0,256K)   G0A uint4[N]  A-frag k0-7 of p_hat (-2-scaled coords)
//          [256,512K) G0B uint4[N]  B-frag k0-7 of p     (raw coords)
//          [512,640K) G1B uint2[N]  B-frag k8-12 payload [zh|nbh, nbm|0]
// d_in[0] (p_hat, 192K): minbuf int[2N] overlay (written only after all reads)
// d_in[1] (p,     192K): G1A uint2[N] overlay   [-2zl|nah, nam|0]
// Slot map (K=32, k = (lane>>4)*8 + j):
//  fA = [-2xh,-2yh,-2zh, -2xh,-2yh,-2zh, -2xl,-2yl | -2zl, nah, nam, 1, 1, 0,0,0 | 0...]
//  fB = [  xh,  yh,  zh,   xl,  yl,  zl,   xh,  yh |   zh,   1,   1, nbh, nbm, 0,0,0 | 0...]
//  dot = -2(hh+hl+lh) + na + nb = |a~-b~|^2 - 2*ll  (ll ~1e-5, zero-mean)

__device__ __forceinline__ unsigned f2bf(float f) {
    unsigned u = __float_as_uint(f);
    return (u + 0x7FFFu + ((u >> 16) & 1u)) >> 16;
}
__device__ __forceinline__ float bf2f(unsigned h) { return __uint_as_float(h << 16); }
__device__ __forceinline__ unsigned pk(unsigned lo, unsigned hi) {
    return (lo & 0xFFFFu) | (hi << 16);
}

// K1: read both clouds -> write ws arrays only (no d_in writes => race-free)
__global__ void pack1_kernel(const float* __restrict__ p_hat,
                             const float* __restrict__ p,
                             uint4* __restrict__ g0a, uint4* __restrict__ g0b,
                             uint2* __restrict__ g1b) {
    int idx = blockIdx.x * blockDim.x + threadIdx.x;
    if (idx >= 2 * N) return;
    int c = idx >> 14, i = idx & (N - 1);
    const float* src = c ? p : p_hat;
    float x = src[3 * i], y = src[3 * i + 1], z = src[3 * i + 2];
    unsigned xh = f2bf(x), yh = f2bf(y), zh = f2bf(z);
    unsigned xl = f2bf(x - bf2f(xh)), yl = f2bf(y - bf2f(yh)), zl = f2bf(z - bf2f(zh));
    if (c == 0) {
        unsigned mxh = f2bf(-2.0f * bf2f(xh)), myh = f2bf(-2.0f * bf2f(yh));
        unsigned mzh = f2bf(-2.0f * bf2f(zh));
        unsigned mxl = f2bf(-2.0f * bf2f(xl)), myl = f2bf(-2.0f * bf2f(yl));
        g0a[i] = make_uint4(pk(mxh, myh), pk(mzh, mxh), pk(myh, mzh), pk(mxl, myl));
    } else {
        g0b[i] = make_uint4(pk(xh, yh), pk(zh, xl), pk(yl, zl), pk(xh, yh));
        float xt = bf2f(xh) + bf2f(xl), yt = bf2f(yh) + bf2f(yl), zt = bf2f(zh) + bf2f(zl);
        float n2 = xt * xt + yt * yt + zt * zt;   // norm of ROUNDED point
        unsigned nh = f2bf(n2);
        unsigned nm = f2bf(n2 - bf2f(nh));
        g1b[i] = make_uint2(pk(zh, nh), pk(nm, 0));
    }
}

// K2a: read p_hat (d_in[0]) -> write G1A overlay on d_in[1] (cross-buffer, ordered)
__global__ void pack2_kernel(const float* __restrict__ p_hat, uint2* __restrict__ g1a) {
    int i = blockIdx.x * blockDim.x + threadIdx.x;
    if (i >= N) return;
    float x = p_hat[3 * i], y = p_hat[3 * i + 1], z = p_hat[3 * i + 2];
    unsigned xh = f2bf(x), yh = f2bf(y), zh = f2bf(z);
    unsigned xl = f2bf(x - bf2f(xh)), yl = f2bf(y - bf2f(yh)), zl = f2bf(z - bf2f(zh));
    unsigned mzl = f2bf(-2.0f * bf2f(zl));
    float xt = bf2f(xh) + bf2f(xl), yt = bf2f(yh) + bf2f(yl), zt = bf2f(zh) + bf2f(zl);
    float n2 = xt * xt + yt * yt + zt * zt;
    unsigned nh = f2bf(n2);
    unsigned nm = f2bf(n2 - bf2f(nh));
    g1a[i] = make_uint2(pk(mzl, nh), pk(nm, 0));
}

// K2b: init minbuf overlay on d_in[0] (runs after all d_in[0] reads)
__global__ void init_kernel(int* __restrict__ minbuf) {
    int idx = blockIdx.x * blockDim.x + threadIdx.x;
    if (idx < 2 * N) minbuf[idx] = INF_BITS;
}

// K3: joint pass — one D tile yields both row-mins (p_hat dir) and col-mins (p dir)
__global__ void __launch_bounds__(256, 2) chamfer_mfma(const uint4* __restrict__ g0a,
                                                       const uint4* __restrict__ g0b,
                                                       const uint2* __restrict__ g1b,
                                                       const uint2* __restrict__ g1a,
                                                       int* __restrict__ minbuf) {
    int ag   = blockIdx.x >> 5;        // a-group [0,16)
    int jc   = blockIdx.x & (JSPLIT - 1);
    int w    = threadIdx.x >> 6;       // wave [0,4)
    int lane = threadIdx.x & 63;
    int g    = lane >> 4, m = lane & 15;

    __shared__ int colmin_lds[JCH * 16];   // 512 cols of this chunk
    for (int k = threadIdx.x; k < JCH * 16; k += 256) colmin_lds[k] = INF_BITS;
    __syncthreads();

    // A fragments: 16 a-tiles resident per wave
    bf16x8 af[AQT];
#pragma unroll
    for (int q = 0; q < AQT; ++q) {
        int t = ag * ABLK + w * AQT + q;
        uint4 d = make_uint4(0, 0, 0, 0);
        if (g == 0) d = g0a[t * 16 + m];
        else if (g == 1) {
            uint2 e = g1a[t * 16 + m];
            d = make_uint4(e.x, pk(e.y, ONE_BF), ONE_BF, 0);  // [-2zl,nah][nam,1][1,0][0,0]
        }
        af[q] = __builtin_bit_cast(bf16x8, d);
    }

    f32x4 zacc = {0.0f, 0.0f, 0.0f, 0.0f};
    int vmin[AQT][4];
#pragma unroll
    for (int q = 0; q < AQT; ++q)
#pragma unroll
        for (int r = 0; r < 4; ++r) vmin[q][r] = INF_BITS;

    for (int tl = 0; tl < JCH; tl += 2) {
        int t0 = jc * JCH + tl;
        // B fragment assembly (b-layout symmetric to A)
        uint4 d0 = make_uint4(0, 0, 0, 0), d1 = make_uint4(0, 0, 0, 0);
        if (g == 0) {
            d0 = g0b[t0 * 16 + m];
            d1 = g0b[(t0 + 1) * 16 + m];
        } else if (g == 1) {
            uint2 e0 = g1b[t0 * 16 + m];
            uint2 e1 = g1b[(t0 + 1) * 16 + m];
            // [zh,1][1,nbh][nbm,0][0,0]
            d0 = make_uint4(pk(e0.x, ONE_BF), (e0.x & 0xFFFF0000u) | ONE_BF, e0.y & 0xFFFFu, 0);
            d1 = make_uint4(pk(e1.x, ONE_BF), (e1.x & 0xFFFF0000u) | ONE_BF, e1.y & 0xFFFFu, 0);
        }
        bf16x8 c0 = __builtin_bit_cast(bf16x8, d0);
        bf16x8 c1 = __builtin_bit_cast(bf16x8, d1);

        int cm0 = INF_BITS, cm1 = INF_BITS;
#pragma unroll
        for (int q = 0; q < AQT; ++q) {
            f32x4 D0 = __builtin_amdgcn_mfma_f32_16x16x32_bf16(af[q], c0, zacc, 0, 0, 0);
            f32x4 D1 = __builtin_amdgcn_mfma_f32_16x16x32_bf16(af[q], c1, zacc, 0, 0, 0);
            int a0 = __float_as_int(D0[0]), a1 = __float_as_int(D0[1]);
            int a2 = __float_as_int(D0[2]), a3 = __float_as_int(D0[3]);
            int b0 = __float_as_int(D1[0]), b1 = __float_as_int(D1[1]);
            int b2 = __float_as_int(D1[2]), b3 = __float_as_int(D1[3]);
            vmin[q][0] = min(vmin[q][0], min(a0, b0));
            vmin[q][1] = min(vmin[q][1], min(a1, b1));
            vmin[q][2] = min(vmin[q][2], min(a2, b2));
            vmin[q][3] = min(vmin[q][3], min(a3, b3));
            cm0 = min(cm0, min(min(a0, a1), min(a2, a3)));
            cm1 = min(cm1, min(min(b0, b1), min(b2, b3)));
        }
        // fold the 4 row-groups, then merge into LDS col-mins
        cm0 = min(cm0, __shfl_xor(cm0, 16, 64));
        cm0 = min(cm0, __shfl_xor(cm0, 32, 64));
        cm1 = min(cm1, __shfl_xor(cm1, 16, 64));
        cm1 = min(cm1, __shfl_xor(cm1, 32, 64));
        if (lane < 16)      atomicMin(&colmin_lds[tl * 16 + m], cm0);
        else if (lane < 32) atomicMin(&colmin_lds[(tl + 1) * 16 + m], cm1);
    }

    // row-direction epilogue (p_hat mins -> minbuf[0,N))
#pragma unroll
    for (int q = 0; q < AQT; ++q) {
#pragma unroll
        for (int r = 0; r < 4; ++r) {
            int v = vmin[q][r];
            v = min(v, __shfl_xor(v, 1, 64));
            v = min(v, __shfl_xor(v, 2, 64));
            v = min(v, __shfl_xor(v, 4, 64));
            v = min(v, __shfl_xor(v, 8, 64));
            if (m == 0) {
                int row = (ag * ABLK + w * AQT + q) * 16 + g * 4 + r;
                atomicMin(&minbuf[row], v);
            }
        }
    }

    // col-direction flush (p mins -> minbuf[N,2N))
    __syncthreads();
    for (int k = threadIdx.x; k < JCH * 16; k += 256)
        atomicMin(&minbuf[N + jc * (JCH * 16) + k], colmin_lds[k]);
}

// K4: out = sum(clamp(mins,0)) / N
__global__ void __launch_bounds__(1024) reduce_kernel(const int* __restrict__ minbuf,
                                                      float* __restrict__ out) {
    const int4* mb4 = (const int4*)minbuf;
    float s = 0.0f;
#pragma unroll
    for (int k = 0; k < (2 * N / 4) / 1024; ++k) {
        int4 v = mb4[k * 1024 + threadIdx.x];
        s += fmaxf(__int_as_float(v.x), 0.0f) + fmaxf(__int_as_float(v.y), 0.0f) +
             fmaxf(__int_as_float(v.z), 0.0f) + fmaxf(__int_as_float(v.w), 0.0f);
    }
    for (int off = 32; off > 0; off >>= 1) s += __shfl_down(s, off, 64);
    __shared__ float partial[16];
    int lane = threadIdx.x & 63, wid = threadIdx.x >> 6;
    if (lane == 0) partial[wid] = s;
    __syncthreads();
    if (threadIdx.x == 0) {
        float t = 0.0f;
        for (int i = 0; i < 16; ++i) t += partial[i];
        out[0] = t / (float)N;
    }
}

extern "C" void kernel_launch(void* const* d_in, const int* in_sizes, int n_in,
                              void* d_out, int out_size, void* d_ws, size_t ws_size,
                              hipStream_t stream) {
    const float* p_hat = (const float*)d_in[0];
    const float* p     = (const float*)d_in[1];
    uint4* g0a = (uint4*)d_ws;                                  // 256 KB
    uint4* g0b = (uint4*)((char*)d_ws + 256 * 1024);            // 256 KB
    uint2* g1b = (uint2*)((char*)d_ws + 512 * 1024);            // 128 KB -> 640 total
    int*   minbuf = (int*)d_in[0];                              // overlay, 128 KB
    uint2* g1a    = (uint2*)d_in[1];                            // overlay, 128 KB
    float* out = (float*)d_out;

    // order matters: all reads of a d_in buffer complete before it's overwritten
    pack1_kernel<<<(2 * N) / 256, 256, 0, stream>>>(p_hat, p, g0a, g0b, g1b);
    pack2_kernel<<<N / 256, 256, 0, stream>>>(p_hat, g1a);       // reads in0, writes in1
    init_kernel<<<(2 * N) / 256, 256, 0, stream>>>(minbuf);      // writes in0
    chamfer_mfma<<<GRID, 256, 0, stream>>>(g0a, g0b, g1b, g1a, minbuf);
    reduce_kernel<<<1, 1024, 0, stream>>>(minbuf, out);
}